// Round 2
// baseline (911.861 us; speedup 1.0000x reference)
//
#include <hip/hip_runtime.h>
#include <math.h>

#define V_NODES 100000
#define E_EDGES 800000
#define HEADS 4
#define FH 32
#define D 128
#define LEAK 0.2f
#define NB 8

// ---------------- Kernel 1: fused QKV projection ----------------
__global__ __launch_bounds__(384) void qkv_kernel(
    const float* __restrict__ h,
    const float* __restrict__ Wq, const float* __restrict__ bq,
    const float* __restrict__ Wk, const float* __restrict__ bk,
    const float* __restrict__ Wv, const float* __restrict__ bv,
    float* __restrict__ Q, float* __restrict__ K, float* __restrict__ Vv)
{
    __shared__ float hsh[D][NB];   // [k][n] transposed
    const int tid  = threadIdx.x;
    const int base = blockIdx.x * NB;

    for (int idx = tid; idx < NB * D; idx += 384) {
        int n = idx >> 7, k = idx & 127;
        hsh[k][n] = h[(long)(base + n) * D + k];
    }
    __syncthreads();

    const int wsel = tid >> 7;      // 0=Q,1=K,2=V  (wave-uniform: 2 waves per sel)
    const int col  = tid & 127;
    const float* W = (wsel == 0) ? Wq : (wsel == 1) ? Wk : Wv;
    const float* b = (wsel == 0) ? bq : (wsel == 1) ? bk : bv;
    float* O       = (wsel == 0) ? Q  : (wsel == 1) ? K  : Vv;

    float acc[NB];
#pragma unroll
    for (int n = 0; n < NB; n++) acc[n] = 0.f;

    for (int k = 0; k < D; k++) {
        float w = W[k * D + col];
#pragma unroll
        for (int n = 0; n < NB; n++) acc[n] += hsh[k][n] * w;
    }

    float bias = b[col];
#pragma unroll
    for (int n = 0; n < NB; n++) O[(long)(base + n) * D + col] = acc[n] + bias;
}

// ---------------- Kernel 2: per-edge multi-head scores ----------------
// 16 lanes per edge; each lane reads 32B of the Q[src]/K[tgt] rows (coalesced
// 512B per 16-lane group), 2-step shfl_xor reduce -> 4 head dots per edge.
__global__ __launch_bounds__(256) void score_kernel(
    const int* __restrict__ src, const int* __restrict__ tgt,
    const float* __restrict__ ew,
    const float* __restrict__ Q, const float* __restrict__ K,
    const float* __restrict__ We, const float* __restrict__ be,
    float* __restrict__ attn_exp)
{
    int t = blockIdx.x * 256 + threadIdx.x;
    int e = t >> 4;
    int sub = t & 15;
    if (e >= E_EDGES) return;
    int s = src[e], tg = tgt[e];
    const float4* q4 = (const float4*)(Q + (long)s * D);
    const float4* k4 = (const float4*)(K + (long)tg * D);
    float4 a0 = q4[sub * 2], a1 = q4[sub * 2 + 1];
    float4 b0 = k4[sub * 2], b1 = k4[sub * 2 + 1];
    float p = a0.x * b0.x + a0.y * b0.y + a0.z * b0.z + a0.w * b0.w
            + a1.x * b1.x + a1.y * b1.y + a1.z * b1.z + a1.w * b1.w;
    p += __shfl_xor(p, 1);
    p += __shfl_xor(p, 2);
    if ((sub & 3) == 0) {
        int hh = sub >> 2;
        float w = ew[e];
        float bias = w * We[hh] + be[hh];
        bias = (bias > 0.f) ? bias : LEAK * bias;
        attn_exp[(long)e * 4 + hh] = __expf(p * 0.17677669529663687f + bias);
    }
}

// ---------------- CSR build: histogram -> scan -> scatter ----------------
__global__ __launch_bounds__(256) void hist_kernel(
    const int* __restrict__ tgt, int* __restrict__ rs)
{
    int e = blockIdx.x * 256 + threadIdx.x;
    if (e < E_EDGES) atomicAdd(&rs[tgt[e]], 1);
}

// Single-block chunked exclusive scan, in place (counts -> row starts).
__global__ __launch_bounds__(1024) void scan_kernel(int* __restrict__ rs)
{
    __shared__ int part[1024];
    const int tid = threadIdx.x;
    const int CH = (V_NODES + 1023) / 1024;   // 98
    int begin = tid * CH;
    int end   = begin + CH; if (end > V_NODES) end = V_NODES;
    if (begin > V_NODES) begin = V_NODES;
    int s = 0;
    for (int i = begin; i < end; i++) s += rs[i];
    part[tid] = s;
    __syncthreads();
    for (int off = 1; off < 1024; off <<= 1) {
        int v = (tid >= off) ? part[tid - off] : 0;
        __syncthreads();
        part[tid] += v;
        __syncthreads();
    }
    int excl = (tid == 0) ? 0 : part[tid - 1];
    for (int i = begin; i < end; i++) {
        int c = rs[i];
        rs[i] = excl;      // exclusive prefix (row start)
        excl += c;
    }
}

// Scatter edge ids into CSR order; rs acts as the cursor and ends as the
// row END pointer array (rs[v] == original rs[v+1] after this kernel).
__global__ __launch_bounds__(256) void scatter_kernel(
    const int* __restrict__ tgt, int* __restrict__ rs, int* __restrict__ csr_e)
{
    int e = blockIdx.x * 256 + threadIdx.x;
    if (e >= E_EDGES) return;
    int pos = atomicAdd(&rs[tgt[e]], 1);
    csr_e[pos] = e;
}

// ---------------- Kernel 3: gather aggregation (no atomics) ----------------
// One wave per target node; lane owns channels {2*lane, 2*lane+1}; per-edge
// Vv row read is one coalesced 512B load; deg accumulated per-lane (own head)
// and divided out at the end.
__global__ __launch_bounds__(256) void agg_kernel(
    const int* __restrict__ rs, const int* __restrict__ csr_e,
    const int* __restrict__ src, const float* __restrict__ ew,
    const float* __restrict__ attn_exp,
    const float* __restrict__ Vv, float* __restrict__ out)
{
    int node = blockIdx.x * 4 + (threadIdx.x >> 6);
    if (node >= V_NODES) return;
    int lane = threadIdx.x & 63;
    int hh = lane >> 4;                 // head of channels 2*lane, 2*lane+1
    int j1 = rs[node];
    int j0 = node ? rs[node - 1] : 0;
    float acc0 = 0.f, acc1 = 0.f, deg = 0.f;
    for (int j = j0; j < j1; j++) {
        int e = csr_e[j];
        float4 att = *((const float4*)(attn_exp + (long)e * 4));
        float atth = (hh == 0) ? att.x : (hh == 1) ? att.y : (hh == 2) ? att.z : att.w;
        deg += atth;
        float w = ew[e];
        if (w != 0.f) {                 // wave-uniform branch
            float2 v = ((const float2*)(Vv + (long)src[e] * D))[lane];
            float a = atth * w;
            acc0 += a * v.x;
            acc1 += a * v.y;
        }
    }
    float inv = 1.f / (deg + 1e-16f);
    ((float2*)(out + (long)node * D))[lane] = make_float2(acc0 * inv, acc1 * inv);
}

// ---------------- Kernel 4: out = LeakyReLU(LayerNorm(agg @ Wo + bo + h)) ----
__global__ __launch_bounds__(128) void out_kernel(
    const float* __restrict__ h, const float* __restrict__ Wo,
    const float* __restrict__ bo, const float* __restrict__ gamma,
    const float* __restrict__ beta, float* __restrict__ out)
{
    __shared__ float ash[D][NB];
    __shared__ float red[2][NB][2];
    const int tid  = threadIdx.x;
    const int base = blockIdx.x * NB;
    const int wave = tid >> 6, lane = tid & 63;

#pragma unroll
    for (int n = 0; n < NB; n++) ash[tid][n] = out[(long)(base + n) * D + tid];
    __syncthreads();

    float acc[NB];
#pragma unroll
    for (int n = 0; n < NB; n++) acc[n] = 0.f;
    for (int k = 0; k < D; k++) {
        float w = Wo[k * D + tid];
#pragma unroll
        for (int n = 0; n < NB; n++) acc[n] += ash[k][n] * w;
    }

    float bb = bo[tid];
    float v[NB];
#pragma unroll
    for (int n = 0; n < NB; n++) {
        v[n] = acc[n] + bb + h[(long)(base + n) * D + tid];
        float s = v[n], q = v[n] * v[n];
#pragma unroll
        for (int off = 32; off; off >>= 1) {
            s += __shfl_xor(s, off);
            q += __shfl_xor(q, off);
        }
        if (lane == 0) { red[wave][n][0] = s; red[wave][n][1] = q; }
    }
    __syncthreads();

    float g = gamma[tid], bt = beta[tid];
#pragma unroll
    for (int n = 0; n < NB; n++) {
        float s  = red[0][n][0] + red[1][n][0];
        float q  = red[0][n][1] + red[1][n][1];
        float mu = s * (1.f / 128.f);
        float var = q * (1.f / 128.f) - mu * mu;
        float rstd = rsqrtf(var + 1e-5f);
        float y = (v[n] - mu) * rstd * g + bt;
        out[(long)(base + n) * D + tid] = (y > 0.f) ? y : LEAK * y;
    }
}

extern "C" void kernel_launch(void* const* d_in, const int* in_sizes, int n_in,
                              void* d_out, int out_size, void* d_ws, size_t ws_size,
                              hipStream_t stream)
{
    const float* h     = (const float*)d_in[0];
    const int*   ei    = (const int*)d_in[1];
    const float* ew    = (const float*)d_in[2];
    const float* Wq    = (const float*)d_in[3];
    const float* bq    = (const float*)d_in[4];
    const float* Wk    = (const float*)d_in[5];
    const float* bk    = (const float*)d_in[6];
    const float* Wv    = (const float*)d_in[7];
    const float* bv    = (const float*)d_in[8];
    const float* Wo    = (const float*)d_in[9];
    const float* bo    = (const float*)d_in[10];
    const float* We    = (const float*)d_in[11];
    const float* be    = (const float*)d_in[12];
    const float* gamma = (const float*)d_in[13];
    const float* beta  = (const float*)d_in[14];
    float* out = (float*)d_out;

    float* Q        = (float*)d_ws;                    // V*128 (dead after score)
    float* K        = Q  + (size_t)V_NODES * D;        // V*128
    float* Vv       = K  + (size_t)V_NODES * D;        // V*128
    float* attn_exp = Vv + (size_t)V_NODES * D;        // E*4

    // CSR scratch aliases the (dead-after-score) Q buffer
    int* rs    = (int*)Q;            // V ints
    int* csr_e = rs + V_NODES;       // E ints  (3.6MB total << 51MB Q region)

    const int* srcp = ei;
    const int* tgtp = ei + E_EDGES;

    qkv_kernel<<<V_NODES / NB, 384, 0, stream>>>(h, Wq, bq, Wk, bk, Wv, bv, Q, K, Vv);
    score_kernel<<<(E_EDGES * 16) / 256, 256, 0, stream>>>(srcp, tgtp, ew, Q, K, We, be, attn_exp);

    hipMemsetAsync(rs, 0, V_NODES * sizeof(int), stream);
    hist_kernel<<<(E_EDGES + 255) / 256, 256, 0, stream>>>(tgtp, rs);
    scan_kernel<<<1, 1024, 0, stream>>>(rs);
    scatter_kernel<<<(E_EDGES + 255) / 256, 256, 0, stream>>>(tgtp, rs, csr_e);

    agg_kernel<<<(V_NODES + 3) / 4, 256, 0, stream>>>(rs, csr_e, srcp, ew, attn_exp, Vv, out);
    out_kernel<<<V_NODES / NB, 128, 0, stream>>>(h, Wo, bo, gamma, beta, out);
}

// Round 5
// 846.990 us; speedup vs baseline: 1.0766x; 1.0766x over previous
//
#include <hip/hip_runtime.h>
#include <math.h>

#define V_NODES 100000
#define E_EDGES 800000
#define HEADS 4
#define D 128
#define LEAK 0.2f
#define NB 8

typedef __attribute__((ext_vector_type(8))) short bf16x8;
typedef __attribute__((ext_vector_type(4))) float f32x4;

__device__ __forceinline__ unsigned short f2bf(float f) {
    unsigned u = __float_as_uint(f);
    u += 0x7FFFu + ((u >> 16) & 1u);       // round-to-nearest-even
    return (unsigned short)(u >> 16);
}

// ---------------- Prep: Wt[384][128] = [Wq|Wk|Wv]^T in bf16 ----------------
__global__ __launch_bounds__(256) void prep_w(
    const float* __restrict__ Wq, const float* __restrict__ Wk,
    const float* __restrict__ Wv,
    unsigned short* __restrict__ Wt)
{
    int idx = blockIdx.x * 256 + threadIdx.x;   // [0, 384*128)
    int c = idx >> 7, k = idx & 127;
    int m = c >> 7, lc = c & 127;
    const float* W = (m == 0) ? Wq : (m == 1) ? Wk : Wv;
    Wt[idx] = f2bf(W[k * D + lc]);
}

// ---------------- Kernel 1 (EXPERIMENTAL): QKV via MFMA (fp32 in/out) --------
// Block = 4 waves over the same 16 rows; wave w covers cols [96w, 96w+96).
__global__ __launch_bounds__(256) void qkv_mfma(
    const float* __restrict__ h, const unsigned short* __restrict__ Wt,
    const float* __restrict__ bq, const float* __restrict__ bk,
    const float* __restrict__ bv,
    float* __restrict__ Q, float* __restrict__ K, float* __restrict__ Vv)
{
    const int wave = threadIdx.x >> 6, lane = threadIdx.x & 63;
    const int row0 = blockIdx.x * 16;
    const int col0 = wave * 96;
    const int r = lane & 15, g = lane >> 4;

    bf16x8 afrag[4];
#pragma unroll
    for (int ks = 0; ks < 4; ks++) {
        const float* ap = h + (long)(row0 + r) * D + ks * 32 + g * 8;
        float4 f0 = *(const float4*)ap;
        float4 f1 = *(const float4*)(ap + 4);
        bf16x8 a;
        a[0] = (short)f2bf(f0.x); a[1] = (short)f2bf(f0.y);
        a[2] = (short)f2bf(f0.z); a[3] = (short)f2bf(f0.w);
        a[4] = (short)f2bf(f1.x); a[5] = (short)f2bf(f1.y);
        a[6] = (short)f2bf(f1.z); a[7] = (short)f2bf(f1.w);
        afrag[ks] = a;
    }

    f32x4 acc[6];
#pragma unroll
    for (int t = 0; t < 6; t++) acc[t] = (f32x4){0.f, 0.f, 0.f, 0.f};

#pragma unroll
    for (int t = 0; t < 6; t++) {
        const unsigned short* bp = Wt + (long)(col0 + t * 16 + r) * D;
#pragma unroll
        for (int ks = 0; ks < 4; ks++) {
            bf16x8 bfrag = *(const bf16x8*)(bp + ks * 32 + g * 8);
            acc[t] = __builtin_amdgcn_mfma_f32_16x16x32_bf16(afrag[ks], bfrag, acc[t], 0, 0, 0);
        }
    }

#pragma unroll
    for (int t = 0; t < 6; t++) {
        int col = col0 + t * 16 + r;
        int m = col >> 7, lc = col & 127;              // wave-uniform per t
        const float* bias = (m == 0) ? bq : (m == 1) ? bk : bv;
        float* O          = (m == 0) ? Q  : (m == 1) ? K  : Vv;
        float bb = bias[lc];
#pragma unroll
        for (int q = 0; q < 4; q++) {
            int R = row0 + g * 4 + q;
            O[(long)R * D + lc] = acc[t][q] + bb;
        }
    }
}

// ---------------- Kernel 2: per-edge multi-head scores (round-2 proven) ------
__global__ __launch_bounds__(256) void score_kernel(
    const int* __restrict__ src, const int* __restrict__ tgt,
    const float* __restrict__ ew,
    const float* __restrict__ Q, const float* __restrict__ K,
    const float* __restrict__ We, const float* __restrict__ be,
    float* __restrict__ attn_exp)
{
    int t = blockIdx.x * 256 + threadIdx.x;
    int e = t >> 4;
    int sub = t & 15;
    if (e >= E_EDGES) return;
    int s = src[e], tg = tgt[e];
    const float4* q4 = (const float4*)(Q + (long)s * D);
    const float4* k4 = (const float4*)(K + (long)tg * D);
    float4 a0 = q4[sub * 2], a1 = q4[sub * 2 + 1];
    float4 b0 = k4[sub * 2], b1 = k4[sub * 2 + 1];
    float p = a0.x * b0.x + a0.y * b0.y + a0.z * b0.z + a0.w * b0.w
            + a1.x * b1.x + a1.y * b1.y + a1.z * b1.z + a1.w * b1.w;
    p += __shfl_xor(p, 1);
    p += __shfl_xor(p, 2);
    if ((sub & 3) == 0) {
        int hh = sub >> 2;
        float w = ew[e];
        float bias = w * We[hh] + be[hh];
        bias = (bias > 0.f) ? bias : LEAK * bias;
        attn_exp[(long)e * 4 + hh] = __expf(p * 0.17677669529663687f + bias);
    }
}

// ---------------- CSR build (round-2 proven) ----------------
__global__ __launch_bounds__(256) void hist_kernel(
    const int* __restrict__ tgt, int* __restrict__ rs)
{
    int e = blockIdx.x * 256 + threadIdx.x;
    if (e < E_EDGES) atomicAdd(&rs[tgt[e]], 1);
}

__global__ __launch_bounds__(1024) void scan_kernel(int* __restrict__ rs)
{
    __shared__ int part[1024];
    const int tid = threadIdx.x;
    const int CH = (V_NODES + 1023) / 1024;
    int begin = tid * CH;
    int end = begin + CH; if (end > V_NODES) end = V_NODES;
    if (begin > V_NODES) begin = V_NODES;
    int s = 0;
    for (int i = begin; i < end; i++) s += rs[i];
    part[tid] = s;
    __syncthreads();
    for (int off = 1; off < 1024; off <<= 1) {
        int v = (tid >= off) ? part[tid - off] : 0;
        __syncthreads();
        part[tid] += v;
        __syncthreads();
    }
    int excl = (tid == 0) ? 0 : part[tid - 1];
    for (int i = begin; i < end; i++) {
        int c = rs[i];
        rs[i] = excl;
        excl += c;
    }
}

__global__ __launch_bounds__(256) void scatter_kernel(
    const int* __restrict__ tgt, int* __restrict__ rs, int* __restrict__ csr_e)
{
    int e = blockIdx.x * 256 + threadIdx.x;
    if (e >= E_EDGES) return;
    int pos = atomicAdd(&rs[tgt[e]], 1);
    csr_e[pos] = e;
}

// ---------------- Kernel 3: gather aggregation (round-2 proven, fp32) --------
__global__ __launch_bounds__(256) void agg_kernel(
    const int* __restrict__ rs, const int* __restrict__ csr_e,
    const int* __restrict__ src, const float* __restrict__ ew,
    const float* __restrict__ attn_exp,
    const float* __restrict__ Vv, float* __restrict__ out)
{
    int node = blockIdx.x * 4 + (threadIdx.x >> 6);
    if (node >= V_NODES) return;
    int lane = threadIdx.x & 63;
    int hh = lane >> 4;
    int j1 = rs[node];
    int j0 = node ? rs[node - 1] : 0;
    float acc0 = 0.f, acc1 = 0.f, deg = 0.f;
    for (int j = j0; j < j1; j++) {
        int e = csr_e[j];
        float4 att = *((const float4*)(attn_exp + (long)e * 4));
        float atth = (hh == 0) ? att.x : (hh == 1) ? att.y : (hh == 2) ? att.z : att.w;
        deg += atth;
        float w = ew[e];
        if (w != 0.f) {
            float2 v = ((const float2*)(Vv + (long)src[e] * D))[lane];
            float a = atth * w;
            acc0 += a * v.x;
            acc1 += a * v.y;
        }
    }
    float inv = 1.f / (deg + 1e-16f);
    ((float2*)(out + (long)node * D))[lane] = make_float2(acc0 * inv, acc1 * inv);
}

// ---------------- Kernel 4: VALU out GEMM + LN (round-2 proven) --------------
__global__ __launch_bounds__(128) void out_kernel(
    const float* __restrict__ h, const float* __restrict__ Wo,
    const float* __restrict__ bo, const float* __restrict__ gamma,
    const float* __restrict__ beta, float* __restrict__ out)
{
    __shared__ float ash[D][NB];
    __shared__ float red[2][NB][2];
    const int tid  = threadIdx.x;
    const int base = blockIdx.x * NB;
    const int wave = tid >> 6, lane = tid & 63;

#pragma unroll
    for (int n = 0; n < NB; n++) ash[tid][n] = out[(long)(base + n) * D + tid];
    __syncthreads();

    float acc[NB];
#pragma unroll
    for (int n = 0; n < NB; n++) acc[n] = 0.f;
    for (int k = 0; k < D; k++) {
        float w = Wo[k * D + tid];
#pragma unroll
        for (int n = 0; n < NB; n++) acc[n] += ash[k][n] * w;
    }

    float bb = bo[tid];
    float v[NB];
#pragma unroll
    for (int n = 0; n < NB; n++) {
        v[n] = acc[n] + bb + h[(long)(base + n) * D + tid];
        float s = v[n], q = v[n] * v[n];
#pragma unroll
        for (int off = 32; off; off >>= 1) {
            s += __shfl_xor(s, off);
            q += __shfl_xor(q, off);
        }
        if (lane == 0) { red[wave][n][0] = s; red[wave][n][1] = q; }
    }
    __syncthreads();

    float g = gamma[tid], bt = beta[tid];
#pragma unroll
    for (int n = 0; n < NB; n++) {
        float s  = red[0][n][0] + red[1][n][0];
        float q  = red[0][n][1] + red[1][n][1];
        float mu = s * (1.f / 128.f);
        float var = q * (1.f / 128.f) - mu * mu;
        float rstd = rsqrtf(var + 1e-5f);
        float y = (v[n] - mu) * rstd * g + bt;
        out[(long)(base + n) * D + tid] = (y > 0.f) ? y : LEAK * y;
    }
}

extern "C" void kernel_launch(void* const* d_in, const int* in_sizes, int n_in,
                              void* d_out, int out_size, void* d_ws, size_t ws_size,
                              hipStream_t stream)
{
    const float* h     = (const float*)d_in[0];
    const int*   ei    = (const int*)d_in[1];
    const float* ew    = (const float*)d_in[2];
    const float* Wq    = (const float*)d_in[3];
    const float* bq    = (const float*)d_in[4];
    const float* Wk    = (const float*)d_in[5];
    const float* bk    = (const float*)d_in[6];
    const float* Wv    = (const float*)d_in[7];
    const float* bv    = (const float*)d_in[8];
    const float* Wo    = (const float*)d_in[9];
    const float* bo    = (const float*)d_in[10];
    const float* We    = (const float*)d_in[11];
    const float* be    = (const float*)d_in[12];
    const float* gamma = (const float*)d_in[13];
    const float* beta  = (const float*)d_in[14];
    float* out = (float*)d_out;

    const size_t VD = (size_t)V_NODES * D;
    // Round-2 layout + Wt at the end (166.5 MB total)
    float* Qf       = (float*)d_ws;                 // VD f32 (dead after score)
    float* Kf       = Qf + VD;
    float* Vf       = Kf + VD;
    float* attn_exp = Vf + VD;                      // E*4 f32
    unsigned short* Wt = (unsigned short*)(attn_exp + (size_t)E_EDGES * 4);
    // CSR scratch aliases the dead Qf region (round-2-identical placement)
    int* rs    = (int*)Qf;           // V ints
    int* csr_e = rs + V_NODES;       // E ints

    const int* srcp = ei;
    const int* tgtp = ei + E_EDGES;

    prep_w<<<(384 * 128) / 256, 256, 0, stream>>>(Wq, Wk, Wv, Wt);
    qkv_mfma<<<V_NODES / 16, 256, 0, stream>>>(h, Wt, bq, bk, bv, Qf, Kf, Vf);
    score_kernel<<<(E_EDGES * 16) / 256, 256, 0, stream>>>(srcp, tgtp, ew, Qf, Kf, We, be, attn_exp);

    hipMemsetAsync(rs, 0, V_NODES * sizeof(int), stream);
    hist_kernel<<<(E_EDGES + 255) / 256, 256, 0, stream>>>(tgtp, rs);
    scan_kernel<<<1, 1024, 0, stream>>>(rs);
    scatter_kernel<<<(E_EDGES + 255) / 256, 256, 0, stream>>>(tgtp, rs, csr_e);

    agg_kernel<<<(V_NODES + 3) / 4, 256, 0, stream>>>(rs, csr_e, srcp, ew, attn_exp, Vf, out);
    out_kernel<<<V_NODES / NB, 128, 0, stream>>>(h, Wo, bo, gamma, beta, out);
}

// Round 6
// 788.579 us; speedup vs baseline: 1.1563x; 1.0741x over previous
//
#include <hip/hip_runtime.h>
#include <math.h>

#define V_NODES 100000
#define E_EDGES 800000
#define HEADS 4
#define D 128
#define LEAK 0.2f
#define NB 8

typedef __attribute__((ext_vector_type(8))) short bf16x8;
typedef __attribute__((ext_vector_type(4))) float f32x4;

__device__ __forceinline__ unsigned short f2bf(float f) {
    unsigned u = __float_as_uint(f);
    u += 0x7FFFu + ((u >> 16) & 1u);       // round-to-nearest-even
    return (unsigned short)(u >> 16);
}

// ---------------- Prep: Wt[384][128] = [Wq|Wk|Wv]^T in bf16 (proven R5) ------
__global__ __launch_bounds__(256) void prep_w(
    const float* __restrict__ Wq, const float* __restrict__ Wk,
    const float* __restrict__ Wv,
    unsigned short* __restrict__ Wt)
{
    int idx = blockIdx.x * 256 + threadIdx.x;   // [0, 384*128)
    int c = idx >> 7, k = idx & 127;
    int m = c >> 7, lc = c & 127;
    const float* W = (m == 0) ? Wq : (m == 1) ? Wk : Wv;
    Wt[idx] = f2bf(W[k * D + lc]);
}

// ---------------- Kernel 1: QKV via MFMA (proven R5) ----------------
__global__ __launch_bounds__(256) void qkv_mfma(
    const float* __restrict__ h, const unsigned short* __restrict__ Wt,
    const float* __restrict__ bq, const float* __restrict__ bk,
    const float* __restrict__ bv,
    float* __restrict__ Q, float* __restrict__ K, float* __restrict__ Vv)
{
    const int wave = threadIdx.x >> 6, lane = threadIdx.x & 63;
    const int row0 = blockIdx.x * 16;
    const int col0 = wave * 96;
    const int r = lane & 15, g = lane >> 4;

    bf16x8 afrag[4];
#pragma unroll
    for (int ks = 0; ks < 4; ks++) {
        const float* ap = h + (long)(row0 + r) * D + ks * 32 + g * 8;
        float4 f0 = *(const float4*)ap;
        float4 f1 = *(const float4*)(ap + 4);
        bf16x8 a;
        a[0] = (short)f2bf(f0.x); a[1] = (short)f2bf(f0.y);
        a[2] = (short)f2bf(f0.z); a[3] = (short)f2bf(f0.w);
        a[4] = (short)f2bf(f1.x); a[5] = (short)f2bf(f1.y);
        a[6] = (short)f2bf(f1.z); a[7] = (short)f2bf(f1.w);
        afrag[ks] = a;
    }

    f32x4 acc[6];
#pragma unroll
    for (int t = 0; t < 6; t++) acc[t] = (f32x4){0.f, 0.f, 0.f, 0.f};

#pragma unroll
    for (int t = 0; t < 6; t++) {
        const unsigned short* bp = Wt + (long)(col0 + t * 16 + r) * D;
#pragma unroll
        for (int ks = 0; ks < 4; ks++) {
            bf16x8 bfrag = *(const bf16x8*)(bp + ks * 32 + g * 8);
            acc[t] = __builtin_amdgcn_mfma_f32_16x16x32_bf16(afrag[ks], bfrag, acc[t], 0, 0, 0);
        }
    }

#pragma unroll
    for (int t = 0; t < 6; t++) {
        int col = col0 + t * 16 + r;
        int m = col >> 7, lc = col & 127;              // wave-uniform per t
        const float* bias = (m == 0) ? bq : (m == 1) ? bk : bv;
        float* O          = (m == 0) ? Q  : (m == 1) ? K  : Vv;
        float bb = bias[lc];
#pragma unroll
        for (int q = 0; q < 4; q++) {
            int R = row0 + g * 4 + q;
            O[(long)R * D + lc] = acc[t][q] + bb;
        }
    }
}

// ---------------- Kernel 2: per-edge multi-head scores (proven R2/R5) --------
__global__ __launch_bounds__(256) void score_kernel(
    const int* __restrict__ src, const int* __restrict__ tgt,
    const float* __restrict__ ew,
    const float* __restrict__ Q, const float* __restrict__ K,
    const float* __restrict__ We, const float* __restrict__ be,
    float* __restrict__ attn_exp)
{
    int t = blockIdx.x * 256 + threadIdx.x;
    int e = t >> 4;
    int sub = t & 15;
    if (e >= E_EDGES) return;
    int s = src[e], tg = tgt[e];
    const float4* q4 = (const float4*)(Q + (long)s * D);
    const float4* k4 = (const float4*)(K + (long)tg * D);
    float4 a0 = q4[sub * 2], a1 = q4[sub * 2 + 1];
    float4 b0 = k4[sub * 2], b1 = k4[sub * 2 + 1];
    float p = a0.x * b0.x + a0.y * b0.y + a0.z * b0.z + a0.w * b0.w
            + a1.x * b1.x + a1.y * b1.y + a1.z * b1.z + a1.w * b1.w;
    p += __shfl_xor(p, 1);
    p += __shfl_xor(p, 2);
    if ((sub & 3) == 0) {
        int hh = sub >> 2;
        float w = ew[e];
        float bias = w * We[hh] + be[hh];
        bias = (bias > 0.f) ? bias : LEAK * bias;
        attn_exp[(long)e * 4 + hh] = __expf(p * 0.17677669529663687f + bias);
    }
}

// ---------------- CSR build (proven R2/R5) ----------------
__global__ __launch_bounds__(256) void hist_kernel(
    const int* __restrict__ tgt, int* __restrict__ rs)
{
    int e = blockIdx.x * 256 + threadIdx.x;
    if (e < E_EDGES) atomicAdd(&rs[tgt[e]], 1);
}

__global__ __launch_bounds__(1024) void scan_kernel(int* __restrict__ rs)
{
    __shared__ int part[1024];
    const int tid = threadIdx.x;
    const int CH = (V_NODES + 1023) / 1024;
    int begin = tid * CH;
    int end = begin + CH; if (end > V_NODES) end = V_NODES;
    if (begin > V_NODES) begin = V_NODES;
    int s = 0;
    for (int i = begin; i < end; i++) s += rs[i];
    part[tid] = s;
    __syncthreads();
    for (int off = 1; off < 1024; off <<= 1) {
        int v = (tid >= off) ? part[tid - off] : 0;
        __syncthreads();
        part[tid] += v;
        __syncthreads();
    }
    int excl = (tid == 0) ? 0 : part[tid - 1];
    for (int i = begin; i < end; i++) {
        int c = rs[i];
        rs[i] = excl;
        excl += c;
    }
}

__global__ __launch_bounds__(256) void scatter_kernel(
    const int* __restrict__ tgt, int* __restrict__ rs, int* __restrict__ csr_e)
{
    int e = blockIdx.x * 256 + threadIdx.x;
    if (e >= E_EDGES) return;
    int pos = atomicAdd(&rs[tgt[e]], 1);
    csr_e[pos] = e;
}

// ---------------- NEW: gather edge data into CSR order ----------------
// csr_srcew[pos] = src | (omega+1)<<24 ; csr_att[pos] = 4 heads of attn as bf16.
__global__ __launch_bounds__(256) void csr_gather(
    const int* __restrict__ csr_e, const int* __restrict__ src,
    const float* __restrict__ ew, const float* __restrict__ attn_exp,
    unsigned* __restrict__ csr_srcew, uint2* __restrict__ csr_att)
{
    int pos = blockIdx.x * 256 + threadIdx.x;
    if (pos >= E_EDGES) return;
    int e = csr_e[pos];
    float4 a = *(const float4*)(attn_exp + (long)e * 4);
    uint2 packed;
    packed.x = (unsigned)f2bf(a.x) | ((unsigned)f2bf(a.y) << 16);
    packed.y = (unsigned)f2bf(a.z) | ((unsigned)f2bf(a.w) << 16);
    csr_att[pos] = packed;
    int s = src[e];
    int w = (int)ew[e] + 1;               // {-1,0,1} -> {0,1,2}
    csr_srcew[pos] = (unsigned)s | ((unsigned)w << 24);
}

// ---------------- NEW: V -> bf16 (halve gather bytes) ----------------
__global__ __launch_bounds__(256) void conv_v(
    const float* __restrict__ Vf, unsigned short* __restrict__ Vb)
{
    long i = ((long)blockIdx.x * 256 + threadIdx.x) * 4;
    float4 v = *(const float4*)(Vf + i);
    ushort4 o;
    o.x = f2bf(v.x); o.y = f2bf(v.y); o.z = f2bf(v.z); o.w = f2bf(v.w);
    *(ushort4*)(Vb + i) = o;
}

// ---------------- Kernel 3: gather aggregation (streamed CSR, bf16 V) --------
// One wave per node; lane owns channels {2*lane, 2*lane+1}. Sequential
// broadcast reads of csr_srcew/csr_att; only Vb row gather is random.
__global__ __launch_bounds__(256) void agg_kernel(
    const int* __restrict__ rs, const unsigned* __restrict__ csr_srcew,
    const uint2* __restrict__ csr_att,
    const unsigned short* __restrict__ Vb, float* __restrict__ out)
{
    int node = blockIdx.x * 4 + (threadIdx.x >> 6);
    if (node >= V_NODES) return;
    int lane = threadIdx.x & 63;
    int hh = lane >> 4;
    int j1 = rs[node];
    int j0 = node ? rs[node - 1] : 0;
    float acc0 = 0.f, acc1 = 0.f, deg = 0.f;
#pragma unroll 2
    for (int j = j0; j < j1; j++) {
        unsigned u = csr_srcew[j];
        uint2 av = csr_att[j];
        unsigned aw = (hh < 2) ? av.x : av.y;
        float atth = __uint_as_float((hh & 1) ? (aw & 0xFFFF0000u) : (aw << 16));
        deg += atth;
        int w = (int)(u >> 24) - 1;
        if (w != 0) {                      // wave-uniform branch
            unsigned vv = *(const unsigned*)(Vb + (long)(u & 0xFFFFFFu) * D + lane * 2);
            float a = atth * (float)w;
            acc0 += a * __uint_as_float(vv << 16);
            acc1 += a * __uint_as_float(vv & 0xFFFF0000u);
        }
    }
    float inv = 1.f / (deg + 1e-16f);
    ((float2*)(out + (long)node * D))[lane] = make_float2(acc0 * inv, acc1 * inv);
}

// ---------------- Kernel 4: VALU out GEMM + LN (proven R2/R5) ----------------
__global__ __launch_bounds__(128) void out_kernel(
    const float* __restrict__ h, const float* __restrict__ Wo,
    const float* __restrict__ bo, const float* __restrict__ gamma,
    const float* __restrict__ beta, float* __restrict__ out)
{
    __shared__ float ash[D][NB];
    __shared__ float red[2][NB][2];
    const int tid  = threadIdx.x;
    const int base = blockIdx.x * NB;
    const int wave = tid >> 6, lane = tid & 63;

#pragma unroll
    for (int n = 0; n < NB; n++) ash[tid][n] = out[(long)(base + n) * D + tid];
    __syncthreads();

    float acc[NB];
#pragma unroll
    for (int n = 0; n < NB; n++) acc[n] = 0.f;
    for (int k = 0; k < D; k++) {
        float w = Wo[k * D + tid];
#pragma unroll
        for (int n = 0; n < NB; n++) acc[n] += ash[k][n] * w;
    }

    float bb = bo[tid];
    float v[NB];
#pragma unroll
    for (int n = 0; n < NB; n++) {
        v[n] = acc[n] + bb + h[(long)(base + n) * D + tid];
        float s = v[n], q = v[n] * v[n];
#pragma unroll
        for (int off = 32; off; off >>= 1) {
            s += __shfl_xor(s, off);
            q += __shfl_xor(q, off);
        }
        if (lane == 0) { red[wave][n][0] = s; red[wave][n][1] = q; }
    }
    __syncthreads();

    float g = gamma[tid], bt = beta[tid];
#pragma unroll
    for (int n = 0; n < NB; n++) {
        float s  = red[0][n][0] + red[1][n][0];
        float q  = red[0][n][1] + red[1][n][1];
        float mu = s * (1.f / 128.f);
        float var = q * (1.f / 128.f) - mu * mu;
        float rstd = rsqrtf(var + 1e-5f);
        float y = (v[n] - mu) * rstd * g + bt;
        out[(long)(base + n) * D + tid] = (y > 0.f) ? y : LEAK * y;
    }
}

extern "C" void kernel_launch(void* const* d_in, const int* in_sizes, int n_in,
                              void* d_out, int out_size, void* d_ws, size_t ws_size,
                              hipStream_t stream)
{
    const float* h     = (const float*)d_in[0];
    const int*   ei    = (const int*)d_in[1];
    const float* ew    = (const float*)d_in[2];
    const float* Wq    = (const float*)d_in[3];
    const float* bq    = (const float*)d_in[4];
    const float* Wk    = (const float*)d_in[5];
    const float* bk    = (const float*)d_in[6];
    const float* Wv    = (const float*)d_in[7];
    const float* bv    = (const float*)d_in[8];
    const float* Wo    = (const float*)d_in[9];
    const float* bo    = (const float*)d_in[10];
    const float* We    = (const float*)d_in[11];
    const float* be    = (const float*)d_in[12];
    const float* gamma = (const float*)d_in[13];
    const float* beta  = (const float*)d_in[14];
    float* out = (float*)d_out;

    const size_t VD = (size_t)V_NODES * D;
    // Round-5-proven footprint (166.5 MB): Qf, Kf, Vf, attn_exp, Wt.
    float* Qf       = (float*)d_ws;                 // VD f32 (dead after score)
    float* Kf       = Qf + VD;
    float* Vf       = Kf + VD;
    float* attn_exp = Vf + VD;                      // E*4 f32
    unsigned short* Wt = (unsigned short*)(attn_exp + (size_t)E_EDGES * 4);

    // Aliases into the dead-after-score Qf region (38.8 MB < 51.2 MB):
    char* qbase = (char*)Qf;
    int*            rs        = (int*)qbase;                        // [0, 0.4M)
    int*            csr_e     = (int*)(qbase + 400000);             // [0.4M, 3.6M)
    unsigned*       csr_srcew = (unsigned*)(qbase + 3600000);       // [3.6M, 6.8M)
    uint2*          csr_att   = (uint2*)(qbase + 6800000);          // [6.8M, 13.2M)
    unsigned short* Vb        = (unsigned short*)(qbase + 13200000);// [13.2M, 38.8M)

    const int* srcp = ei;
    const int* tgtp = ei + E_EDGES;

    prep_w<<<(384 * 128) / 256, 256, 0, stream>>>(Wq, Wk, Wv, Wt);
    qkv_mfma<<<V_NODES / 16, 256, 0, stream>>>(h, Wt, bq, bk, bv, Qf, Kf, Vf);
    score_kernel<<<(E_EDGES * 16) / 256, 256, 0, stream>>>(srcp, tgtp, ew, Qf, Kf, We, be, attn_exp);

    // CSR build + stream preparation (Qf dead from here on)
    hipMemsetAsync(rs, 0, V_NODES * sizeof(int), stream);
    hist_kernel<<<(E_EDGES + 255) / 256, 256, 0, stream>>>(tgtp, rs);
    scan_kernel<<<1, 1024, 0, stream>>>(rs);
    scatter_kernel<<<(E_EDGES + 255) / 256, 256, 0, stream>>>(tgtp, rs, csr_e);
    csr_gather<<<E_EDGES / 256, 256, 0, stream>>>(csr_e, srcp, ew, attn_exp, csr_srcew, csr_att);
    conv_v<<<(int)(VD / 4 / 256), 256, 0, stream>>>(Vf, Vb);

    agg_kernel<<<(V_NODES + 3) / 4, 256, 0, stream>>>(rs, csr_srcew, csr_att, Vb, out);
    out_kernel<<<V_NODES / NB, 128, 0, stream>>>(h, Wo, bo, gamma, beta, out);
}